// Round 7
// baseline (387.029 us; speedup 1.0000x reference)
//
#include <hip/hip_runtime.h>

#define N_PTS 1600
#define NSIDE 40
#define SNUM  512
#define BNUM  64
#define C1D   20
#define WID   128

typedef _Float16 h8  __attribute__((ext_vector_type(8)));
typedef __fp16   h2v __attribute__((ext_vector_type(2)));   // type for cvt_pkrtz/fdot2
typedef float    f4  __attribute__((ext_vector_type(4)));

__device__ __forceinline__ float silu_f(float x){ return x / (1.f + __expf(-x)); }
__device__ __forceinline__ void fma4(float4& a, float s, const float4 w){
    a.x += s*w.x; a.y += s*w.y; a.z += s*w.z; a.w += s*w.w;
}

// ---------------------------------------------------------------------------
// KA: blocks 0..319: filt2[s][c*128+w] = h2[s] @ s_w2 + s_b2 with h2 computed
//     inline per 16-s tile (h2 = silu(v0e @ s_w1 + s_b1), sincos+doubling).
//     blocks 320..369: pack data[64][1600] fp32 -> dataA f16 MFMA A-fragments
//     (layout verified round 4/6): dataA[(chunk*4+mt)*64+lane][8],
//     b = mt*16+(lane&15), n = chunk*32+(lane>>4)*8+j.
// ---------------------------------------------------------------------------
__global__ __launch_bounds__(256) void ka_prep(
    const float* __restrict__ data, const float* __restrict__ v0,
    const float* __restrict__ s_w1, const float* __restrict__ s_b1,
    const float* __restrict__ s_w2, const float* __restrict__ s_b2,
    _Float16* __restrict__ dataA, float* __restrict__ f2g)
{
    const int t  = threadIdx.x;
    const int bx = blockIdx.x;
    if (bx >= 320) {
        const int o  = (bx - 320) * 256 + t;       // 0..12799
        const int L  = o & 63, cm = o >> 6;        // cm 0..199
        const int mt = cm & 3, ch = cm >> 2;       // ch 0..49
        const int b  = mt * 16 + (L & 15);
        const int nb = ch * 32 + (L >> 4) * 8;
        const float* src = data + b * N_PTS + nb;
        h8 v;
        #pragma unroll
        for (int j = 0; j < 8; j++) v[j] = (_Float16)src[j];
        *(h8*)(dataA + (size_t)o * 8) = v;
        return;
    }
    const int st  = bx / 10, ct = bx - st * 10;
    const int s0  = st * 16;
    const int col = ct * 256 + t;
    __shared__ __align__(16) float h2t[128][20];   // [i][ss] pad 20 (16B-aligned rows)

    for (int idx = t; idx < 2048; idx += 256) {
        const int ss = idx >> 7, j = idx & 127;
        float acc = s_b1[j];
        #pragma unroll
        for (int d = 0; d < 8; d++) {
            const float val = v0[(s0 + ss) * 8 + d];
            float sv, cv;
            __sincosf(val, &sv, &cv);
            #pragma unroll
            for (int k = 0; k < 5; k++) {
                acc += sv * s_w1[(d*10 + k)     * WID + j];
                acc += cv * s_w1[(d*10 + 5 + k) * WID + j];
                const float ns = 2.f * sv * cv;
                const float nc = 1.f - 2.f * sv * sv;
                sv = ns; cv = nc;
            }
        }
        h2t[j][ss] = silu_f(acc);
    }
    __syncthreads();

    float4 acc[4];
    #pragma unroll
    for (int qq = 0; qq < 4; qq++) acc[qq] = make_float4(0.f, 0.f, 0.f, 0.f);
    #pragma unroll 4
    for (int i = 0; i < 128; i++) {
        const float wv = s_w2[i * 2560 + col];
        const float4* hh = (const float4*)&h2t[i][0];
        #pragma unroll
        for (int qq = 0; qq < 4; qq++) fma4(acc[qq], wv, hh[qq]);
    }
    const float bias = s_b2[col];
    const float* af = (const float*)acc;
    #pragma unroll
    for (int ss = 0; ss < 16; ss++)
        f2g[(s0 + ss) * 2560 + col] = af[ss] + bias;
}

// ---------------------------------------------------------------------------
// K1 helpers
// ---------------------------------------------------------------------------
__device__ __forceinline__ void embed_pt(int n, const float Hm[9], h2v e2[10])
{
    const int i = n / NSIDE;
    const int j = n - i * NSIDE;
    const float x = -1.f + (float)i * (2.f/39.f);
    const float y = -1.f + (float)j * (2.f/39.f);
    const float y0 = Hm[0]*x + Hm[1]*y + Hm[2];
    const float y1 = Hm[3]*x + Hm[4]*y + Hm[5];
    const float y2 = Hm[6]*x + Hm[7]*y + Hm[8];
    const float inv = 1.f / y2;
    const float t0 = y0 * inv, t1 = y1 * inv;
    float e[20];
    float sv0, cv0, sv1, cv1;
    __sincosf(t0, &sv0, &cv0);
    __sincosf(t1, &sv1, &cv1);
    #pragma unroll
    for (int k = 0; k < 5; k++) {
        e[k] = sv0; e[5+k] = cv0; e[10+k] = sv1; e[15+k] = cv1;
        const float ns0 = 2.f*sv0*cv0, nc0 = 1.f - 2.f*sv0*sv0; sv0 = ns0; cv0 = nc0;
        const float ns1 = 2.f*sv1*cv1, nc1 = 1.f - 2.f*sv1*sv1; sv1 = ns1; cv1 = nc1;
    }
    #pragma unroll
    for (int k = 0; k < 10; k++)
        e2[k] = __builtin_amdgcn_cvt_pkrtz(e[2*k], e[2*k+1]);
}

// one 20->20 layer for two points; weights read ONCE (b128 broadcast), fdot2
__device__ __forceinline__ void layer20(const h2v e2a[10], const h2v e2b[10],
    const h2v (*wL)[20], const float* bL, float hA[20], float hB[20])
{
    #pragma unroll
    for (int qq = 0; qq < 5; qq++) {
        const f4 bvv = ((const f4*)bL)[qq];
        hA[4*qq+0] = bvv[0]; hA[4*qq+1] = bvv[1]; hA[4*qq+2] = bvv[2]; hA[4*qq+3] = bvv[3];
        hB[4*qq+0] = bvv[0]; hB[4*qq+1] = bvv[1]; hB[4*qq+2] = bvv[2]; hB[4*qq+3] = bvv[3];
    }
    #pragma unroll
    for (int k = 0; k < 10; k++) {
        const uint4* Wp = (const uint4*)&wL[k][0];
        const h2v ea = e2a[k], eb = e2b[k];
        #pragma unroll
        for (int qq = 0; qq < 5; qq++) {
            const uint4 Wv = Wp[qq];
            const h2v w0 = __builtin_bit_cast(h2v, Wv.x);
            const h2v w1 = __builtin_bit_cast(h2v, Wv.y);
            const h2v w2 = __builtin_bit_cast(h2v, Wv.z);
            const h2v w3 = __builtin_bit_cast(h2v, Wv.w);
            hA[4*qq+0] = __builtin_amdgcn_fdot2(ea, w0, hA[4*qq+0], false);
            hA[4*qq+1] = __builtin_amdgcn_fdot2(ea, w1, hA[4*qq+1], false);
            hA[4*qq+2] = __builtin_amdgcn_fdot2(ea, w2, hA[4*qq+2], false);
            hA[4*qq+3] = __builtin_amdgcn_fdot2(ea, w3, hA[4*qq+3], false);
            hB[4*qq+0] = __builtin_amdgcn_fdot2(eb, w0, hB[4*qq+0], false);
            hB[4*qq+1] = __builtin_amdgcn_fdot2(eb, w1, hB[4*qq+1], false);
            hB[4*qq+2] = __builtin_amdgcn_fdot2(eb, w2, hB[4*qq+2], false);
            hB[4*qq+3] = __builtin_amdgcn_fdot2(eb, w3, hB[4*qq+3], false);
        }
    }
}

// ---------------------------------------------------------------------------
// K1: grid 1024 = (half, s). Per block: 800 points in tiles {512, 288}.
// MLP on VALU (f16x2 dot2, P=2), filt -> LDS B-layout [c][p] f16,
// z-GEMM via MFMA with global A-frags. zpart[half][s][c*64+b] raw sums.
// __launch_bounds__(256,3): trim VGPR to <=170 -> 3 waves/SIMD.
// ---------------------------------------------------------------------------
__global__ __launch_bounds__(256, 3) void k1_filt_z(
    const _Float16* __restrict__ dataA, const float* __restrict__ v_last,
    const float* __restrict__ w1, const float* __restrict__ b1,
    const float* __restrict__ w2, const float* __restrict__ b2,
    const float* __restrict__ w3, const float* __restrict__ b3,
    float* __restrict__ zpart)
{
    const int s    = blockIdx.x & 511;
    const int half = blockIdx.x >> 9;
    const int nb0  = half * 800;
    const int t    = threadIdx.x;
    const int lane = t & 63;
    const int w    = t >> 6;
    const int q    = lane >> 4;
    const int l15  = lane & 15;

    __shared__ __align__(16) h2v   wW[3][10][20];     // 2400 B packed (cin-pair, cout)
    __shared__ __align__(16) float lbias[3][20];      //  240 B
    __shared__ __align__(16) unsigned char pool[21504];
    _Float16* filtB = (_Float16*)pool;                // [20][520] = 20800 B
    float*    red   = (float*)pool;                   // [4][64][21] (after last MFMA)

    const float* wsrc[3] = { w1, w2, w3 };
    const float* bsrc[3] = { b1, b2, b3 };
    for (int v = t; v < 600; v += 256) {
        const int l = v / 200, rem = v - l*200;
        const int k = rem / 20, c = rem - k*20;
        wW[l][k][c] = __builtin_amdgcn_cvt_pkrtz(wsrc[l][(2*k)*20 + c],
                                                 wsrc[l][(2*k+1)*20 + c]);
    }
    if (t < 60) lbias[t/20][t%20] = bsrc[t/20][t%20];

    float Hm[9];
    #pragma unroll
    for (int k = 0; k < 9; k++) Hm[k] = (k == 0 || k == 4 || k == 8) ? 1.f : 0.f;
    #pragma unroll
    for (int k = 0; k < 8; k++) Hm[k] += 0.1f * v_last[s*8 + k];

    f4 zacc[4][2];
    #pragma unroll
    for (int mt = 0; mt < 4; mt++) { zacc[mt][0] = (f4)(0.f); zacc[mt][1] = (f4)(0.f); }

    __syncthreads();

    for (int base = 0; base < 800; base += 512) {
        const int tn = min(512, 800 - base);     // 512, 288
        if (t < tn) {
            const bool a1 = (t + 256) < tn;
            const int n0 = nb0 + base + t;
            const int n1 = a1 ? (n0 + 256) : n0;
            h2v e2a[10], e2b[10];
            embed_pt(n0, Hm, e2a);
            embed_pt(n1, Hm, e2b);
            float hA[20], hB[20];
            layer20(e2a, e2b, wW[0], lbias[0], hA, hB);
            #pragma unroll
            for (int k = 0; k < 10; k++) {
                e2a[k] = __builtin_amdgcn_cvt_pkrtz(silu_f(hA[2*k]), silu_f(hA[2*k+1]));
                e2b[k] = __builtin_amdgcn_cvt_pkrtz(silu_f(hB[2*k]), silu_f(hB[2*k+1]));
            }
            layer20(e2a, e2b, wW[1], lbias[1], hA, hB);
            #pragma unroll
            for (int k = 0; k < 10; k++) {
                e2a[k] = __builtin_amdgcn_cvt_pkrtz(silu_f(hA[2*k]), silu_f(hA[2*k+1]));
                e2b[k] = __builtin_amdgcn_cvt_pkrtz(silu_f(hB[2*k]), silu_f(hB[2*k+1]));
            }
            layer20(e2a, e2b, wW[2], lbias[2], hA, hB);
            #pragma unroll
            for (int c = 0; c < 20; c++) {
                filtB[c*520 + t] = (_Float16)hA[c];
                if (a1) filtB[c*520 + 256 + t] = (_Float16)hB[c];
            }
        }
        __syncthreads();

        const int nkc = tn >> 5;   // 16, 9
        const int r1row = (l15 < 4) ? (16 + l15) : 0;
        for (int kc = w; kc < nkc; kc += 4) {
            const int gchunk = ((nb0 + base) >> 5) + kc;
            const h8 bf0 = *(const h8*)&filtB[(size_t)l15  * 520 + kc*32 + q*8];
            const h8 bf1 = *(const h8*)&filtB[(size_t)r1row* 520 + kc*32 + q*8];
            #pragma unroll
            for (int mt = 0; mt < 4; mt++) {
                const h8 afz = *(const h8*)(dataA + ((size_t)(gchunk*4 + mt)*64 + lane)*8);
                zacc[mt][0] = __builtin_amdgcn_mfma_f32_16x16x32_f16(afz, bf0, zacc[mt][0], 0, 0, 0);
                zacc[mt][1] = __builtin_amdgcn_mfma_f32_16x16x32_f16(afz, bf1, zacc[mt][1], 0, 0, 0);
            }
        }
        __syncthreads();
    }

    // cross-wave K-reduction (red overlays filtB; safe after trailing barrier)
    #pragma unroll
    for (int mt = 0; mt < 4; mt++) {
        #pragma unroll
        for (int r = 0; r < 4; r++) {
            const int b = mt*16 + q*4 + r;
            red[(w*64 + b)*21 + l15] = zacc[mt][0][r];
            if (l15 < 4) red[(w*64 + b)*21 + 16 + l15] = zacc[mt][1][r];
        }
    }
    __syncthreads();
    for (int v = t; v < 1280; v += 256) {
        const int c = v >> 6, b = v & 63;
        const float sum = red[b*21 + c] + red[(64+b)*21 + c]
                        + red[(128+b)*21 + c] + red[(192+b)*21 + c];
        zpart[(half*512 + s)*1280 + v] = sum;   // raw; silu + /N applied in k2
    }
}

// ---------------------------------------------------------------------------
// K2: grid 256 = (sgrp 128) x (whalf 2). Block: 4 s, 64 w.
// Combines zpart halves + silu + /N, contracts vs filt2 -> part[blk][b][w64]
// ---------------------------------------------------------------------------
__global__ __launch_bounds__(256) void k2_contract(
    const float* __restrict__ zg, const float* __restrict__ f2g,
    float* __restrict__ part)
{
    const int blk = blockIdx.x;
    const int sg  = blk >> 1;
    const int wh  = blk & 1;
    const int s0  = sg * 4;
    const int w0  = wh * 64;
    const int t   = threadIdx.x;
    __shared__ __align__(16) float zl[4*1280];   // [sp][c][b]
    __shared__ __align__(16) float fl[4*20*64];  // [sp][c][w64]
    #pragma unroll
    for (int sp = 0; sp < 4; sp++) {
        const int srow = (s0 + sp) * 1280;
        for (int r = t; r < 1280; r += 256) {
            const float a0 = zg[srow + r];
            const float a1 = zg[512*1280 + srow + r];
            zl[sp*1280 + r] = silu_f((a0 + a1) * (1.f / (float)N_PTS));
        }
        for (int u = t; u < 1280; u += 256) {
            const int c = u >> 6, ww = u & 63;
            fl[sp*1280 + u] = f2g[(s0 + sp)*2560 + c*128 + w0 + ww];
        }
    }
    __syncthreads();
    const int ww = t & 63, bh = t >> 6;
    float4 acc[4];
    #pragma unroll
    for (int qq = 0; qq < 4; qq++) acc[qq] = make_float4(0.f, 0.f, 0.f, 0.f);
    #pragma unroll 4
    for (int sc = 0; sc < 80; sc++) {
        const float f = fl[sc * 64 + ww];
        const float4* zz = (const float4*)&zl[sc * 64 + bh * 16];
        #pragma unroll
        for (int qq = 0; qq < 4; qq++) fma4(acc[qq], f, zz[qq]);
    }
    const float* af = (const float*)acc;
    #pragma unroll
    for (int idx = 0; idx < 16; idx++) {
        const int b = bh * 16 + idx;
        part[blk * 4096 + b * 64 + ww] = af[idx];
    }
}

// ---------------------------------------------------------------------------
// K3: reduce partials over 128 s-groups, then FC tail.
// ---------------------------------------------------------------------------
__global__ __launch_bounds__(128) void k3_tail(
    const float* __restrict__ part,
    const float* __restrict__ fc1w, const float* __restrict__ fc1b,
    const float* __restrict__ fc2w, const float* __restrict__ fc2b,
    const float* __restrict__ pw,   const float* __restrict__ pb,
    float* __restrict__ out)
{
    const int b = blockIdx.x, t = threadIdx.x;
    const int wh = t >> 6, wl = t & 63;
    __shared__ float zb[128], r1[128], r2[128];
    float sum = 0.f;
    #pragma unroll 8
    for (int sg = 0; sg < 128; sg++)
        sum += part[((sg << 1) | wh) * 4096 + b * 64 + wl];
    zb[t] = sum * (1.f / (float)SNUM);
    __syncthreads();
    float a = fc1b[t];
    #pragma unroll 8
    for (int i = 0; i < 128; i++) a += zb[i] * fc1w[i * 128 + t];
    r1[t] = silu_f(a) + zb[t];
    __syncthreads();
    a = fc2b[t];
    #pragma unroll 8
    for (int i = 0; i < 128; i++) a += r1[i] * fc2w[i * 128 + t];
    r2[t] = silu_f(a) + r1[t];
    __syncthreads();
    if (t < 10) {
        float o = pb[t];
        #pragma unroll 8
        for (int i = 0; i < 128; i++) o += r2[i] * pw[i * 10 + t];
        out[b * 10 + t] = o;
    }
}

extern "C" void kernel_launch(void* const* d_in, const int* in_sizes, int n_in,
                              void* d_out, int out_size, void* d_ws, size_t ws_size,
                              hipStream_t stream) {
    const float* data   = (const float*)d_in[0];
    const float* v0     = (const float*)d_in[1];
    const float* v_last = (const float*)d_in[2];
    const float* fl_w1  = (const float*)d_in[3];
    const float* fl_b1  = (const float*)d_in[4];
    const float* fl_w2  = (const float*)d_in[5];
    const float* fl_b2  = (const float*)d_in[6];
    const float* fl_w3  = (const float*)d_in[7];
    const float* fl_b3  = (const float*)d_in[8];
    const float* s_w1   = (const float*)d_in[9];
    const float* s_b1   = (const float*)d_in[10];
    const float* s_w2   = (const float*)d_in[11];
    const float* s_b2   = (const float*)d_in[12];
    const float* fc1_w  = (const float*)d_in[13];
    const float* fc1_b  = (const float*)d_in[14];
    const float* fc2_w  = (const float*)d_in[15];
    const float* fc2_b  = (const float*)d_in[16];
    const float* pool_w = (const float*)d_in[17];
    const float* pool_b = (const float*)d_in[18];
    float* out = (float*)d_out;

    float* ws       = (float*)d_ws;
    _Float16* dataA = (_Float16*)ws;        // 102400 halves = 51200 float slots
    float* zpart = ws    + 51200;           // 2*655360 [half][s][c][b] raw
    float* f2g   = zpart + 1310720;         // 1310720  [s][c*128+w]
    float* part  = f2g   + 1310720;         // 1048576  [blk][b][w64]
    // total 3,721,216 floats = 14.9 MB

    ka_prep    <<<370, 256, 0, stream>>>(data, v0, s_w1, s_b1, s_w2, s_b2,
                                         dataA, f2g);
    k1_filt_z  <<<1024, 256, 0, stream>>>(dataA, v_last, fl_w1, fl_b1, fl_w2, fl_b2,
                                          fl_w3, fl_b3, zpart);
    k2_contract<<<256, 256, 0, stream>>>(zpart, f2g, part);
    k3_tail    <<<64, 128, 0, stream>>>(part, fc1_w, fc1_b, fc2_w, fc2_b,
                                        pool_w, pool_b, out);
}

// Round 8
// 224.153 us; speedup vs baseline: 1.7266x; 1.7266x over previous
//
#include <hip/hip_runtime.h>

#define N_PTS 1600
#define NSIDE 40
#define SNUM  512
#define BNUM  64
#define C1D   20
#define WID   128

typedef _Float16 h8  __attribute__((ext_vector_type(8)));
typedef __fp16   h2v __attribute__((ext_vector_type(2)));   // type for cvt_pkrtz/fdot2
typedef float    f4  __attribute__((ext_vector_type(4)));

__device__ __forceinline__ float silu_f(float x){ return x / (1.f + __expf(-x)); }
__device__ __forceinline__ void fma4(float4& a, float s, const float4 w){
    a.x += s*w.x; a.y += s*w.y; a.z += s*w.z; a.w += s*w.w;
}

// ---------------------------------------------------------------------------
// KA: blocks 0..319: filt2[s][c*128+w] = h2[s] @ s_w2 + s_b2 with h2 computed
//     inline per 16-s tile. blocks 320..369: pack data -> dataA f16 MFMA
//     A-fragments (layout verified rounds 4/6). block 370: pack MLP weights
//     (f16-pair, [l][k][c]) + biases into global for K1's uniform loads.
// ---------------------------------------------------------------------------
__global__ __launch_bounds__(256) void ka_prep(
    const float* __restrict__ data, const float* __restrict__ v0,
    const float* __restrict__ s_w1, const float* __restrict__ s_b1,
    const float* __restrict__ s_w2, const float* __restrict__ s_b2,
    const float* __restrict__ w1, const float* __restrict__ b1,
    const float* __restrict__ w2, const float* __restrict__ b2,
    const float* __restrict__ w3, const float* __restrict__ b3,
    _Float16* __restrict__ dataA, float* __restrict__ f2g,
    h2v* __restrict__ wPack, float* __restrict__ bPack)
{
    const int t  = threadIdx.x;
    const int bx = blockIdx.x;
    if (bx == 370) {
        const float* wsrc[3] = { w1, w2, w3 };
        const float* bsrc[3] = { b1, b2, b3 };
        for (int v = t; v < 600; v += 256) {
            const int l = v / 200, rem = v - l*200;
            const int k = rem / 20, c = rem - k*20;
            wPack[v] = __builtin_amdgcn_cvt_pkrtz(wsrc[l][(2*k)*20 + c],
                                                  wsrc[l][(2*k+1)*20 + c]);
        }
        if (t < 60) bPack[t] = bsrc[t/20][t%20];
        return;
    }
    if (bx >= 320) {
        const int o  = (bx - 320) * 256 + t;       // 0..12799
        const int L  = o & 63, cm = o >> 6;        // cm 0..199
        const int mt = cm & 3, ch = cm >> 2;       // ch 0..49
        const int b  = mt * 16 + (L & 15);
        const int nb = ch * 32 + (L >> 4) * 8;
        const float* src = data + b * N_PTS + nb;
        h8 v;
        #pragma unroll
        for (int j = 0; j < 8; j++) v[j] = (_Float16)src[j];
        *(h8*)(dataA + (size_t)o * 8) = v;
        return;
    }
    const int st  = bx / 10, ct = bx - st * 10;
    const int s0  = st * 16;
    const int col = ct * 256 + t;
    __shared__ __align__(16) float h2t[128][20];   // [i][ss] pad 20

    for (int idx = t; idx < 2048; idx += 256) {
        const int ss = idx >> 7, j = idx & 127;
        float acc = s_b1[j];
        #pragma unroll
        for (int d = 0; d < 8; d++) {
            const float val = v0[(s0 + ss) * 8 + d];
            float sv, cv;
            __sincosf(val, &sv, &cv);
            #pragma unroll
            for (int k = 0; k < 5; k++) {
                acc += sv * s_w1[(d*10 + k)     * WID + j];
                acc += cv * s_w1[(d*10 + 5 + k) * WID + j];
                const float ns = 2.f * sv * cv;
                const float nc = 1.f - 2.f * sv * sv;
                sv = ns; cv = nc;
            }
        }
        h2t[j][ss] = silu_f(acc);
    }
    __syncthreads();

    float4 acc[4];
    #pragma unroll
    for (int qq = 0; qq < 4; qq++) acc[qq] = make_float4(0.f, 0.f, 0.f, 0.f);
    #pragma unroll 4
    for (int i = 0; i < 128; i++) {
        const float wv = s_w2[i * 2560 + col];
        const float4* hh = (const float4*)&h2t[i][0];
        #pragma unroll
        for (int qq = 0; qq < 4; qq++) fma4(acc[qq], wv, hh[qq]);
    }
    const float bias = s_b2[col];
    const float* af = (const float*)acc;
    #pragma unroll
    for (int ss = 0; ss < 16; ss++)
        f2g[(s0 + ss) * 2560 + col] = af[ss] + bias;
}

// ---------------------------------------------------------------------------
// K1 helpers
// ---------------------------------------------------------------------------
__device__ __forceinline__ void embed_pt(int n, const float Hm[9], h2v e2[10])
{
    const int i = n / NSIDE;
    const int j = n - i * NSIDE;
    const float x = -1.f + (float)i * (2.f/39.f);
    const float y = -1.f + (float)j * (2.f/39.f);
    const float y0 = Hm[0]*x + Hm[1]*y + Hm[2];
    const float y1 = Hm[3]*x + Hm[4]*y + Hm[5];
    const float y2 = Hm[6]*x + Hm[7]*y + Hm[8];
    const float inv = 1.f / y2;
    const float t0 = y0 * inv, t1 = y1 * inv;
    float e[20];
    float sv0, cv0, sv1, cv1;
    __sincosf(t0, &sv0, &cv0);
    __sincosf(t1, &sv1, &cv1);
    #pragma unroll
    for (int k = 0; k < 5; k++) {
        e[k] = sv0; e[5+k] = cv0; e[10+k] = sv1; e[15+k] = cv1;
        const float ns0 = 2.f*sv0*cv0, nc0 = 1.f - 2.f*sv0*sv0; sv0 = ns0; cv0 = nc0;
        const float ns1 = 2.f*sv1*cv1, nc1 = 1.f - 2.f*sv1*sv1; sv1 = ns1; cv1 = nc1;
    }
    #pragma unroll
    for (int k = 0; k < 10; k++)
        e2[k] = __builtin_amdgcn_cvt_pkrtz(e[2*k], e[2*k+1]);
}

// one 20->20 layer for two points; weights from GLOBAL (uniform address ->
// scalar/constant-cache loads, zero DS traffic), fdot2 accumulate in fp32.
__device__ __forceinline__ void layer20(const h2v e2a[10], const h2v e2b[10],
    const h2v* __restrict__ wL, const float* __restrict__ bL,
    float hA[20], float hB[20])
{
    #pragma unroll
    for (int qq = 0; qq < 5; qq++) {
        const f4 bvv = ((const f4*)bL)[qq];
        hA[4*qq+0] = bvv[0]; hA[4*qq+1] = bvv[1]; hA[4*qq+2] = bvv[2]; hA[4*qq+3] = bvv[3];
        hB[4*qq+0] = bvv[0]; hB[4*qq+1] = bvv[1]; hB[4*qq+2] = bvv[2]; hB[4*qq+3] = bvv[3];
    }
    #pragma unroll
    for (int k = 0; k < 10; k++) {
        const uint4* Wp = (const uint4*)(wL + k*20);
        const h2v ea = e2a[k], eb = e2b[k];
        #pragma unroll
        for (int qq = 0; qq < 5; qq++) {
            const uint4 Wv = Wp[qq];
            const h2v w0 = __builtin_bit_cast(h2v, Wv.x);
            const h2v w1 = __builtin_bit_cast(h2v, Wv.y);
            const h2v w2 = __builtin_bit_cast(h2v, Wv.z);
            const h2v w3 = __builtin_bit_cast(h2v, Wv.w);
            hA[4*qq+0] = __builtin_amdgcn_fdot2(ea, w0, hA[4*qq+0], false);
            hA[4*qq+1] = __builtin_amdgcn_fdot2(ea, w1, hA[4*qq+1], false);
            hA[4*qq+2] = __builtin_amdgcn_fdot2(ea, w2, hA[4*qq+2], false);
            hA[4*qq+3] = __builtin_amdgcn_fdot2(ea, w3, hA[4*qq+3], false);
            hB[4*qq+0] = __builtin_amdgcn_fdot2(eb, w0, hB[4*qq+0], false);
            hB[4*qq+1] = __builtin_amdgcn_fdot2(eb, w1, hB[4*qq+1], false);
            hB[4*qq+2] = __builtin_amdgcn_fdot2(eb, w2, hB[4*qq+2], false);
            hB[4*qq+3] = __builtin_amdgcn_fdot2(eb, w3, hB[4*qq+3], false);
        }
    }
}

// ---------------------------------------------------------------------------
// K1: one block per s (grid 512, round-6 config: natural VGPR, no min-waves).
// MLP on VALU (f16x2 dot2, P=2), weights from global (no LDS), filt -> LDS
// B-layout [c][p] f16, z-GEMM via MFMA with global A-frags.
// Tiles of 512 points (3x512 + 64 tail). zg[s][c*64+b] final (silu applied).
// ---------------------------------------------------------------------------
__global__ __launch_bounds__(256) void k1_filt_z(
    const _Float16* __restrict__ dataA, const float* __restrict__ v_last,
    const h2v* __restrict__ wPack, const float* __restrict__ bPack,
    float* __restrict__ zg)
{
    const int s    = blockIdx.x;
    const int t    = threadIdx.x;
    const int lane = t & 63;
    const int w    = t >> 6;
    const int q    = lane >> 4;
    const int l15  = lane & 15;

    __shared__ __align__(16) unsigned char pool[21504];
    _Float16* filtB = (_Float16*)pool;                // [20][520] = 20800 B
    float*    red   = (float*)pool;                   // [4][64][21] (after last MFMA)

    float Hm[9];
    #pragma unroll
    for (int k = 0; k < 9; k++) Hm[k] = (k == 0 || k == 4 || k == 8) ? 1.f : 0.f;
    #pragma unroll
    for (int k = 0; k < 8; k++) Hm[k] += 0.1f * v_last[s*8 + k];

    f4 zacc[4][2];
    #pragma unroll
    for (int mt = 0; mt < 4; mt++) { zacc[mt][0] = (f4)(0.f); zacc[mt][1] = (f4)(0.f); }

    for (int base = 0; base < N_PTS; base += 512) {
        const int tn = min(512, N_PTS - base);     // 512,512,512,64
        if (t < tn) {
            const bool a1 = (t + 256) < tn;
            const int n0 = base + t;
            const int n1 = a1 ? (n0 + 256) : n0;
            h2v e2a[10], e2b[10];
            embed_pt(n0, Hm, e2a);
            embed_pt(n1, Hm, e2b);
            float hA[20], hB[20];
            layer20(e2a, e2b, wPack +   0, bPack +  0, hA, hB);
            #pragma unroll
            for (int k = 0; k < 10; k++) {
                e2a[k] = __builtin_amdgcn_cvt_pkrtz(silu_f(hA[2*k]), silu_f(hA[2*k+1]));
                e2b[k] = __builtin_amdgcn_cvt_pkrtz(silu_f(hB[2*k]), silu_f(hB[2*k+1]));
            }
            layer20(e2a, e2b, wPack + 200, bPack + 20, hA, hB);
            #pragma unroll
            for (int k = 0; k < 10; k++) {
                e2a[k] = __builtin_amdgcn_cvt_pkrtz(silu_f(hA[2*k]), silu_f(hA[2*k+1]));
                e2b[k] = __builtin_amdgcn_cvt_pkrtz(silu_f(hB[2*k]), silu_f(hB[2*k+1]));
            }
            layer20(e2a, e2b, wPack + 400, bPack + 40, hA, hB);
            #pragma unroll
            for (int c = 0; c < 20; c++) {
                filtB[c*520 + t] = (_Float16)hA[c];
                if (a1) filtB[c*520 + 256 + t] = (_Float16)hB[c];
            }
        }
        __syncthreads();

        const int nkc = tn >> 5;   // 16,16,16,2
        const int r1row = (l15 < 4) ? (16 + l15) : 0;
        for (int kc = w; kc < nkc; kc += 4) {
            const int gchunk = (base >> 5) + kc;
            const h8 bf0 = *(const h8*)&filtB[(size_t)l15  * 520 + kc*32 + q*8];
            const h8 bf1 = *(const h8*)&filtB[(size_t)r1row* 520 + kc*32 + q*8];
            #pragma unroll
            for (int mt = 0; mt < 4; mt++) {
                const h8 afz = *(const h8*)(dataA + ((size_t)(gchunk*4 + mt)*64 + lane)*8);
                zacc[mt][0] = __builtin_amdgcn_mfma_f32_16x16x32_f16(afz, bf0, zacc[mt][0], 0, 0, 0);
                zacc[mt][1] = __builtin_amdgcn_mfma_f32_16x16x32_f16(afz, bf1, zacc[mt][1], 0, 0, 0);
            }
        }
        __syncthreads();
    }

    // cross-wave K-reduction (red overlays filtB; safe after trailing barrier)
    #pragma unroll
    for (int mt = 0; mt < 4; mt++) {
        #pragma unroll
        for (int r = 0; r < 4; r++) {
            const int b = mt*16 + q*4 + r;
            red[(w*64 + b)*21 + l15] = zacc[mt][0][r];
            if (l15 < 4) red[(w*64 + b)*21 + 16 + l15] = zacc[mt][1][r];
        }
    }
    __syncthreads();
    for (int v = t; v < 1280; v += 256) {
        const int c = v >> 6, b = v & 63;
        const float sum = red[b*21 + c] + red[(64+b)*21 + c]
                        + red[(128+b)*21 + c] + red[(192+b)*21 + c];
        zg[s*1280 + v] = silu_f(sum * (1.f / (float)N_PTS));
    }
}

// ---------------------------------------------------------------------------
// K2: grid 256 = (sgrp 128) x (whalf 2). Block: 4 s, 64 w. part[blk][b][w64]
// ---------------------------------------------------------------------------
__global__ __launch_bounds__(256) void k2_contract(
    const float* __restrict__ zg, const float* __restrict__ f2g,
    float* __restrict__ part)
{
    const int blk = blockIdx.x;
    const int sg  = blk >> 1;
    const int wh  = blk & 1;
    const int s0  = sg * 4;
    const int w0  = wh * 64;
    const int t   = threadIdx.x;
    __shared__ __align__(16) float zl[4*1280];   // [sp][c][b]
    __shared__ __align__(16) float fl[4*20*64];  // [sp][c][w64]
    #pragma unroll
    for (int sp = 0; sp < 4; sp++) {
        const int srow = (s0 + sp) * 1280;
        for (int r = t; r < 1280; r += 256)
            zl[sp*1280 + r] = zg[srow + r];
        for (int u = t; u < 1280; u += 256) {
            const int c = u >> 6, ww = u & 63;
            fl[sp*1280 + u] = f2g[(s0 + sp)*2560 + c*128 + w0 + ww];
        }
    }
    __syncthreads();
    const int ww = t & 63, bh = t >> 6;
    float4 acc[4];
    #pragma unroll
    for (int qq = 0; qq < 4; qq++) acc[qq] = make_float4(0.f, 0.f, 0.f, 0.f);
    #pragma unroll 4
    for (int sc = 0; sc < 80; sc++) {
        const float f = fl[sc * 64 + ww];
        const float4* zz = (const float4*)&zl[sc * 64 + bh * 16];
        #pragma unroll
        for (int qq = 0; qq < 4; qq++) fma4(acc[qq], f, zz[qq]);
    }
    const float* af = (const float*)acc;
    #pragma unroll
    for (int idx = 0; idx < 16; idx++) {
        const int b = bh * 16 + idx;
        part[blk * 4096 + b * 64 + ww] = af[idx];
    }
}

// ---------------------------------------------------------------------------
// K3: reduce partials over 128 s-groups, then FC tail.
// ---------------------------------------------------------------------------
__global__ __launch_bounds__(128) void k3_tail(
    const float* __restrict__ part,
    const float* __restrict__ fc1w, const float* __restrict__ fc1b,
    const float* __restrict__ fc2w, const float* __restrict__ fc2b,
    const float* __restrict__ pw,   const float* __restrict__ pb,
    float* __restrict__ out)
{
    const int b = blockIdx.x, t = threadIdx.x;
    const int wh = t >> 6, wl = t & 63;
    __shared__ float zb[128], r1[128], r2[128];
    float sum = 0.f;
    #pragma unroll 8
    for (int sg = 0; sg < 128; sg++)
        sum += part[((sg << 1) | wh) * 4096 + b * 64 + wl];
    zb[t] = sum * (1.f / (float)SNUM);
    __syncthreads();
    float a = fc1b[t];
    #pragma unroll 8
    for (int i = 0; i < 128; i++) a += zb[i] * fc1w[i * 128 + t];
    r1[t] = silu_f(a) + zb[t];
    __syncthreads();
    a = fc2b[t];
    #pragma unroll 8
    for (int i = 0; i < 128; i++) a += r1[i] * fc2w[i * 128 + t];
    r2[t] = silu_f(a) + r1[t];
    __syncthreads();
    if (t < 10) {
        float o = pb[t];
        #pragma unroll 8
        for (int i = 0; i < 128; i++) o += r2[i] * pw[i * 10 + t];
        out[b * 10 + t] = o;
    }
}

extern "C" void kernel_launch(void* const* d_in, const int* in_sizes, int n_in,
                              void* d_out, int out_size, void* d_ws, size_t ws_size,
                              hipStream_t stream) {
    const float* data   = (const float*)d_in[0];
    const float* v0     = (const float*)d_in[1];
    const float* v_last = (const float*)d_in[2];
    const float* fl_w1  = (const float*)d_in[3];
    const float* fl_b1  = (const float*)d_in[4];
    const float* fl_w2  = (const float*)d_in[5];
    const float* fl_b2  = (const float*)d_in[6];
    const float* fl_w3  = (const float*)d_in[7];
    const float* fl_b3  = (const float*)d_in[8];
    const float* s_w1   = (const float*)d_in[9];
    const float* s_b1   = (const float*)d_in[10];
    const float* s_w2   = (const float*)d_in[11];
    const float* s_b2   = (const float*)d_in[12];
    const float* fc1_w  = (const float*)d_in[13];
    const float* fc1_b  = (const float*)d_in[14];
    const float* fc2_w  = (const float*)d_in[15];
    const float* fc2_b  = (const float*)d_in[16];
    const float* pool_w = (const float*)d_in[17];
    const float* pool_b = (const float*)d_in[18];
    float* out = (float*)d_out;

    float* ws       = (float*)d_ws;
    _Float16* dataA = (_Float16*)ws;        // 102400 halves = 51200 float slots
    float* zg    = ws    + 51200;           // 655360  [s][c][b] (final z)
    float* f2g   = zg    + 655360;          // 1310720 [s][c*128+w]
    float* part  = f2g   + 1310720;         // 1048576 [blk][b][w64]
    h2v*   wPack = (h2v*)(part + 1048576);  // 600 h2v = 600 float slots... (2400 B)
    float* bPack = (float*)(wPack + 600);   // 60 floats
    // total ~12.3 MB

    ka_prep    <<<371, 256, 0, stream>>>(data, v0, s_w1, s_b1, s_w2, s_b2,
                                         fl_w1, fl_b1, fl_w2, fl_b2, fl_w3, fl_b3,
                                         dataA, f2g, wPack, bPack);
    k1_filt_z  <<<512, 256, 0, stream>>>(dataA, v_last, wPack, bPack, zg);
    k2_contract<<<256, 256, 0, stream>>>(zg, f2g, part);
    k3_tail    <<<64, 128, 0, stream>>>(part, fc1_w, fc1_b, fc2_w, fc2_b,
                                        pool_w, pool_b, out);
}

// Round 9
// 220.859 us; speedup vs baseline: 1.7524x; 1.0149x over previous
//
#include <hip/hip_runtime.h>

#define N_PTS 1600
#define NSIDE 40
#define SNUM  512
#define BNUM  64
#define C1D   20
#define WID   128

typedef _Float16 h8  __attribute__((ext_vector_type(8)));
typedef __fp16   h2v __attribute__((ext_vector_type(2)));   // type for cvt_pkrtz/fdot2
typedef float    f4  __attribute__((ext_vector_type(4)));

__device__ __forceinline__ float silu_f(float x){ return x / (1.f + __expf(-x)); }
__device__ __forceinline__ void fma4(float4& a, float s, const float4 w){
    a.x += s*w.x; a.y += s*w.y; a.z += s*w.z; a.w += s*w.w;
}

// ---------------------------------------------------------------------------
// KA: blocks 0..319: filt2[s][c*128+w] = h2[s] @ s_w2 + s_b2 with h2 computed
//     inline per 16-s tile. blocks 320..369: pack data -> dataA f16 MFMA
//     A-fragments (layout verified rounds 4/6). block 370: pack MLP weights
//     (f16-pair, [l][k][c]) + biases into global for K1's uniform loads.
// ---------------------------------------------------------------------------
__global__ __launch_bounds__(256) void ka_prep(
    const float* __restrict__ data, const float* __restrict__ v0,
    const float* __restrict__ s_w1, const float* __restrict__ s_b1,
    const float* __restrict__ s_w2, const float* __restrict__ s_b2,
    const float* __restrict__ w1, const float* __restrict__ b1,
    const float* __restrict__ w2, const float* __restrict__ b2,
    const float* __restrict__ w3, const float* __restrict__ b3,
    _Float16* __restrict__ dataA, float* __restrict__ f2g,
    h2v* __restrict__ wPack, float* __restrict__ bPack)
{
    const int t  = threadIdx.x;
    const int bx = blockIdx.x;
    if (bx == 370) {
        const float* wsrc[3] = { w1, w2, w3 };
        const float* bsrc[3] = { b1, b2, b3 };
        for (int v = t; v < 600; v += 256) {
            const int l = v / 200, rem = v - l*200;
            const int k = rem / 20, c = rem - k*20;
            wPack[v] = __builtin_amdgcn_cvt_pkrtz(wsrc[l][(2*k)*20 + c],
                                                  wsrc[l][(2*k+1)*20 + c]);
        }
        if (t < 60) bPack[t] = bsrc[t/20][t%20];
        return;
    }
    if (bx >= 320) {
        const int o  = (bx - 320) * 256 + t;       // 0..12799
        const int L  = o & 63, cm = o >> 6;        // cm 0..199
        const int mt = cm & 3, ch = cm >> 2;       // ch 0..49
        const int b  = mt * 16 + (L & 15);
        const int nb = ch * 32 + (L >> 4) * 8;
        const float* src = data + b * N_PTS + nb;
        h8 v;
        #pragma unroll
        for (int j = 0; j < 8; j++) v[j] = (_Float16)src[j];
        *(h8*)(dataA + (size_t)o * 8) = v;
        return;
    }
    const int st  = bx / 10, ct = bx - st * 10;
    const int s0  = st * 16;
    const int col = ct * 256 + t;
    __shared__ __align__(16) float h2t[128][20];   // [i][ss] pad 20

    for (int idx = t; idx < 2048; idx += 256) {
        const int ss = idx >> 7, j = idx & 127;
        float acc = s_b1[j];
        #pragma unroll
        for (int d = 0; d < 8; d++) {
            const float val = v0[(s0 + ss) * 8 + d];
            float sv, cv;
            __sincosf(val, &sv, &cv);
            #pragma unroll
            for (int k = 0; k < 5; k++) {
                acc += sv * s_w1[(d*10 + k)     * WID + j];
                acc += cv * s_w1[(d*10 + 5 + k) * WID + j];
                const float ns = 2.f * sv * cv;
                const float nc = 1.f - 2.f * sv * sv;
                sv = ns; cv = nc;
            }
        }
        h2t[j][ss] = silu_f(acc);
    }
    __syncthreads();

    float4 acc[4];
    #pragma unroll
    for (int qq = 0; qq < 4; qq++) acc[qq] = make_float4(0.f, 0.f, 0.f, 0.f);
    #pragma unroll 4
    for (int i = 0; i < 128; i++) {
        const float wv = s_w2[i * 2560 + col];
        const float4* hh = (const float4*)&h2t[i][0];
        #pragma unroll
        for (int qq = 0; qq < 4; qq++) fma4(acc[qq], wv, hh[qq]);
    }
    const float bias = s_b2[col];
    const float* af = (const float*)acc;
    #pragma unroll
    for (int ss = 0; ss < 16; ss++)
        f2g[(s0 + ss) * 2560 + col] = af[ss] + bias;
}

// ---------------------------------------------------------------------------
// K1 helpers
// ---------------------------------------------------------------------------
__device__ __forceinline__ void embed_pt(int n, const float Hm[9], h2v e2[10])
{
    const int i = n / NSIDE;
    const int j = n - i * NSIDE;
    const float x = -1.f + (float)i * (2.f/39.f);
    const float y = -1.f + (float)j * (2.f/39.f);
    const float y0 = Hm[0]*x + Hm[1]*y + Hm[2];
    const float y1 = Hm[3]*x + Hm[4]*y + Hm[5];
    const float y2 = Hm[6]*x + Hm[7]*y + Hm[8];
    const float inv = 1.f / y2;
    const float t0 = y0 * inv, t1 = y1 * inv;
    float e[20];
    float sv0, cv0, sv1, cv1;
    __sincosf(t0, &sv0, &cv0);
    __sincosf(t1, &sv1, &cv1);
    #pragma unroll
    for (int k = 0; k < 5; k++) {
        e[k] = sv0; e[5+k] = cv0; e[10+k] = sv1; e[15+k] = cv1;
        const float ns0 = 2.f*sv0*cv0, nc0 = 1.f - 2.f*sv0*sv0; sv0 = ns0; cv0 = nc0;
        const float ns1 = 2.f*sv1*cv1, nc1 = 1.f - 2.f*sv1*sv1; sv1 = ns1; cv1 = nc1;
    }
    #pragma unroll
    for (int k = 0; k < 10; k++)
        e2[k] = __builtin_amdgcn_cvt_pkrtz(e[2*k], e[2*k+1]);
}

// one 20->20 layer for two points; weights from GLOBAL (uniform address ->
// L1-cached broadcast loads, zero DS traffic), fdot2 accumulate in fp32.
__device__ __forceinline__ void layer20(const h2v e2a[10], const h2v e2b[10],
    const h2v* __restrict__ wL, const float* __restrict__ bL,
    float hA[20], float hB[20])
{
    #pragma unroll
    for (int qq = 0; qq < 5; qq++) {
        const f4 bvv = ((const f4*)bL)[qq];
        hA[4*qq+0] = bvv[0]; hA[4*qq+1] = bvv[1]; hA[4*qq+2] = bvv[2]; hA[4*qq+3] = bvv[3];
        hB[4*qq+0] = bvv[0]; hB[4*qq+1] = bvv[1]; hB[4*qq+2] = bvv[2]; hB[4*qq+3] = bvv[3];
    }
    #pragma unroll
    for (int k = 0; k < 10; k++) {
        const uint4* Wp = (const uint4*)(wL + k*20);
        const h2v ea = e2a[k], eb = e2b[k];
        #pragma unroll
        for (int qq = 0; qq < 5; qq++) {
            const uint4 Wv = Wp[qq];
            const h2v w0 = __builtin_bit_cast(h2v, Wv.x);
            const h2v w1 = __builtin_bit_cast(h2v, Wv.y);
            const h2v w2 = __builtin_bit_cast(h2v, Wv.z);
            const h2v w3 = __builtin_bit_cast(h2v, Wv.w);
            hA[4*qq+0] = __builtin_amdgcn_fdot2(ea, w0, hA[4*qq+0], false);
            hA[4*qq+1] = __builtin_amdgcn_fdot2(ea, w1, hA[4*qq+1], false);
            hA[4*qq+2] = __builtin_amdgcn_fdot2(ea, w2, hA[4*qq+2], false);
            hA[4*qq+3] = __builtin_amdgcn_fdot2(ea, w3, hA[4*qq+3], false);
            hB[4*qq+0] = __builtin_amdgcn_fdot2(eb, w0, hB[4*qq+0], false);
            hB[4*qq+1] = __builtin_amdgcn_fdot2(eb, w1, hB[4*qq+1], false);
            hB[4*qq+2] = __builtin_amdgcn_fdot2(eb, w2, hB[4*qq+2], false);
            hB[4*qq+3] = __builtin_amdgcn_fdot2(eb, w3, hB[4*qq+3], false);
        }
    }
}

// ---------------------------------------------------------------------------
// K1: grid 1024 = (half, s). 800 points/block in tiles {512, 288}.
// Round-8 body (VGPR 68) + round-3 n-split for 4 blocks/CU occupancy.
// zpart[half][s][c*64+b] raw sums; K2 combines + silu + /N.
// ---------------------------------------------------------------------------
__global__ __launch_bounds__(256) void k1_filt_z(
    const _Float16* __restrict__ dataA, const float* __restrict__ v_last,
    const h2v* __restrict__ wPack, const float* __restrict__ bPack,
    float* __restrict__ zpart)
{
    const int s    = blockIdx.x & 511;
    const int half = blockIdx.x >> 9;
    const int nb0  = half * 800;
    const int t    = threadIdx.x;
    const int lane = t & 63;
    const int w    = t >> 6;
    const int q    = lane >> 4;
    const int l15  = lane & 15;

    __shared__ __align__(16) unsigned char pool[21504];
    _Float16* filtB = (_Float16*)pool;                // [20][520] = 20800 B
    float*    red   = (float*)pool;                   // [4][64][21] (after last MFMA)

    float Hm[9];
    #pragma unroll
    for (int k = 0; k < 9; k++) Hm[k] = (k == 0 || k == 4 || k == 8) ? 1.f : 0.f;
    #pragma unroll
    for (int k = 0; k < 8; k++) Hm[k] += 0.1f * v_last[s*8 + k];

    f4 zacc[4][2];
    #pragma unroll
    for (int mt = 0; mt < 4; mt++) { zacc[mt][0] = (f4)(0.f); zacc[mt][1] = (f4)(0.f); }

    for (int base = 0; base < 800; base += 512) {
        const int tn = min(512, 800 - base);     // 512, 288
        if (t < tn) {
            const bool a1 = (t + 256) < tn;
            const int n0 = nb0 + base + t;
            const int n1 = a1 ? (n0 + 256) : n0;
            h2v e2a[10], e2b[10];
            embed_pt(n0, Hm, e2a);
            embed_pt(n1, Hm, e2b);
            float hA[20], hB[20];
            layer20(e2a, e2b, wPack +   0, bPack +  0, hA, hB);
            #pragma unroll
            for (int k = 0; k < 10; k++) {
                e2a[k] = __builtin_amdgcn_cvt_pkrtz(silu_f(hA[2*k]), silu_f(hA[2*k+1]));
                e2b[k] = __builtin_amdgcn_cvt_pkrtz(silu_f(hB[2*k]), silu_f(hB[2*k+1]));
            }
            layer20(e2a, e2b, wPack + 200, bPack + 20, hA, hB);
            #pragma unroll
            for (int k = 0; k < 10; k++) {
                e2a[k] = __builtin_amdgcn_cvt_pkrtz(silu_f(hA[2*k]), silu_f(hA[2*k+1]));
                e2b[k] = __builtin_amdgcn_cvt_pkrtz(silu_f(hB[2*k]), silu_f(hB[2*k+1]));
            }
            layer20(e2a, e2b, wPack + 400, bPack + 40, hA, hB);
            #pragma unroll
            for (int c = 0; c < 20; c++) {
                filtB[c*520 + t] = (_Float16)hA[c];
                if (a1) filtB[c*520 + 256 + t] = (_Float16)hB[c];
            }
        }
        __syncthreads();

        const int nkc = tn >> 5;   // 16, 9
        const int r1row = (l15 < 4) ? (16 + l15) : 0;
        for (int kc = w; kc < nkc; kc += 4) {
            const int gchunk = ((nb0 + base) >> 5) + kc;
            const h8 bf0 = *(const h8*)&filtB[(size_t)l15  * 520 + kc*32 + q*8];
            const h8 bf1 = *(const h8*)&filtB[(size_t)r1row* 520 + kc*32 + q*8];
            #pragma unroll
            for (int mt = 0; mt < 4; mt++) {
                const h8 afz = *(const h8*)(dataA + ((size_t)(gchunk*4 + mt)*64 + lane)*8);
                zacc[mt][0] = __builtin_amdgcn_mfma_f32_16x16x32_f16(afz, bf0, zacc[mt][0], 0, 0, 0);
                zacc[mt][1] = __builtin_amdgcn_mfma_f32_16x16x32_f16(afz, bf1, zacc[mt][1], 0, 0, 0);
            }
        }
        __syncthreads();
    }

    // cross-wave K-reduction (red overlays filtB; safe after trailing barrier)
    #pragma unroll
    for (int mt = 0; mt < 4; mt++) {
        #pragma unroll
        for (int r = 0; r < 4; r++) {
            const int b = mt*16 + q*4 + r;
            red[(w*64 + b)*21 + l15] = zacc[mt][0][r];
            if (l15 < 4) red[(w*64 + b)*21 + 16 + l15] = zacc[mt][1][r];
        }
    }
    __syncthreads();
    for (int v = t; v < 1280; v += 256) {
        const int c = v >> 6, b = v & 63;
        const float sum = red[b*21 + c] + red[(64+b)*21 + c]
                        + red[(128+b)*21 + c] + red[(192+b)*21 + c];
        zpart[(half*512 + s)*1280 + v] = sum;   // raw; silu + /N applied in k2
    }
}

// ---------------------------------------------------------------------------
// K2: grid 256 = (sgrp 128) x (whalf 2). Block: 4 s, 64 w.
// Combines zpart halves + silu + /N, contracts vs filt2 -> part[blk][b][w64]
// ---------------------------------------------------------------------------
__global__ __launch_bounds__(256) void k2_contract(
    const float* __restrict__ zg, const float* __restrict__ f2g,
    float* __restrict__ part)
{
    const int blk = blockIdx.x;
    const int sg  = blk >> 1;
    const int wh  = blk & 1;
    const int s0  = sg * 4;
    const int w0  = wh * 64;
    const int t   = threadIdx.x;
    __shared__ __align__(16) float zl[4*1280];   // [sp][c][b]
    __shared__ __align__(16) float fl[4*20*64];  // [sp][c][w64]
    #pragma unroll
    for (int sp = 0; sp < 4; sp++) {
        const int srow = (s0 + sp) * 1280;
        for (int r = t; r < 1280; r += 256) {
            const float a0 = zg[srow + r];
            const float a1 = zg[512*1280 + srow + r];
            zl[sp*1280 + r] = silu_f((a0 + a1) * (1.f / (float)N_PTS));
        }
        for (int u = t; u < 1280; u += 256) {
            const int c = u >> 6, ww = u & 63;
            fl[sp*1280 + u] = f2g[(s0 + sp)*2560 + c*128 + w0 + ww];
        }
    }
    __syncthreads();
    const int ww = t & 63, bh = t >> 6;
    float4 acc[4];
    #pragma unroll
    for (int qq = 0; qq < 4; qq++) acc[qq] = make_float4(0.f, 0.f, 0.f, 0.f);
    #pragma unroll 4
    for (int sc = 0; sc < 80; sc++) {
        const float f = fl[sc * 64 + ww];
        const float4* zz = (const float4*)&zl[sc * 64 + bh * 16];
        #pragma unroll
        for (int qq = 0; qq < 4; qq++) fma4(acc[qq], f, zz[qq]);
    }
    const float* af = (const float*)acc;
    #pragma unroll
    for (int idx = 0; idx < 16; idx++) {
        const int b = bh * 16 + idx;
        part[blk * 4096 + b * 64 + ww] = af[idx];
    }
}

// ---------------------------------------------------------------------------
// K3: reduce partials over 128 s-groups, then FC tail.
// ---------------------------------------------------------------------------
__global__ __launch_bounds__(128) void k3_tail(
    const float* __restrict__ part,
    const float* __restrict__ fc1w, const float* __restrict__ fc1b,
    const float* __restrict__ fc2w, const float* __restrict__ fc2b,
    const float* __restrict__ pw,   const float* __restrict__ pb,
    float* __restrict__ out)
{
    const int b = blockIdx.x, t = threadIdx.x;
    const int wh = t >> 6, wl = t & 63;
    __shared__ float zb[128], r1[128], r2[128];
    float sum = 0.f;
    #pragma unroll 8
    for (int sg = 0; sg < 128; sg++)
        sum += part[((sg << 1) | wh) * 4096 + b * 64 + wl];
    zb[t] = sum * (1.f / (float)SNUM);
    __syncthreads();
    float a = fc1b[t];
    #pragma unroll 8
    for (int i = 0; i < 128; i++) a += zb[i] * fc1w[i * 128 + t];
    r1[t] = silu_f(a) + zb[t];
    __syncthreads();
    a = fc2b[t];
    #pragma unroll 8
    for (int i = 0; i < 128; i++) a += r1[i] * fc2w[i * 128 + t];
    r2[t] = silu_f(a) + r1[t];
    __syncthreads();
    if (t < 10) {
        float o = pb[t];
        #pragma unroll 8
        for (int i = 0; i < 128; i++) o += r2[i] * pw[i * 10 + t];
        out[b * 10 + t] = o;
    }
}

extern "C" void kernel_launch(void* const* d_in, const int* in_sizes, int n_in,
                              void* d_out, int out_size, void* d_ws, size_t ws_size,
                              hipStream_t stream) {
    const float* data   = (const float*)d_in[0];
    const float* v0     = (const float*)d_in[1];
    const float* v_last = (const float*)d_in[2];
    const float* fl_w1  = (const float*)d_in[3];
    const float* fl_b1  = (const float*)d_in[4];
    const float* fl_w2  = (const float*)d_in[5];
    const float* fl_b2  = (const float*)d_in[6];
    const float* fl_w3  = (const float*)d_in[7];
    const float* fl_b3  = (const float*)d_in[8];
    const float* s_w1   = (const float*)d_in[9];
    const float* s_b1   = (const float*)d_in[10];
    const float* s_w2   = (const float*)d_in[11];
    const float* s_b2   = (const float*)d_in[12];
    const float* fc1_w  = (const float*)d_in[13];
    const float* fc1_b  = (const float*)d_in[14];
    const float* fc2_w  = (const float*)d_in[15];
    const float* fc2_b  = (const float*)d_in[16];
    const float* pool_w = (const float*)d_in[17];
    const float* pool_b = (const float*)d_in[18];
    float* out = (float*)d_out;

    float* ws       = (float*)d_ws;
    _Float16* dataA = (_Float16*)ws;        // 102400 halves = 51200 float slots
    float* zpart = ws    + 51200;           // 2*655360 [half][s][c][b] raw
    float* f2g   = zpart + 1310720;         // 1310720  [s][c*128+w]
    float* part  = f2g   + 1310720;         // 1048576  [blk][b][w64]
    h2v*   wPack = (h2v*)(part + 1048576);  // 2400 B
    float* bPack = (float*)(wPack + 600);   // 60 floats
    // total ~14.9 MB

    ka_prep    <<<371, 256, 0, stream>>>(data, v0, s_w1, s_b1, s_w2, s_b2,
                                         fl_w1, fl_b1, fl_w2, fl_b2, fl_w3, fl_b3,
                                         dataA, f2g, wPack, bPack);
    k1_filt_z  <<<1024, 256, 0, stream>>>(dataA, v_last, wPack, bPack, zpart);
    k2_contract<<<256, 256, 0, stream>>>(zpart, f2g, part);
    k3_tail    <<<64, 128, 0, stream>>>(part, fc1_w, fc1_b, fc2_w, fc2_b,
                                        pool_w, pool_b, out);
}

// Round 10
// 197.096 us; speedup vs baseline: 1.9637x; 1.1206x over previous
//
#include <hip/hip_runtime.h>

#define N_PTS 1600
#define NSIDE 40
#define SNUM  512
#define BNUM  64
#define C1D   20
#define WID   128

typedef _Float16 h8  __attribute__((ext_vector_type(8)));
typedef _Float16 h4  __attribute__((ext_vector_type(4)));
typedef __fp16   h2v __attribute__((ext_vector_type(2)));   // type for cvt_pkrtz
typedef float    f4  __attribute__((ext_vector_type(4)));

__device__ __forceinline__ float silu_f(float x){ return x / (1.f + __expf(-x)); }
__device__ __forceinline__ void fma4(float4& a, float s, const float4 w){
    a.x += s*w.x; a.y += s*w.y; a.z += s*w.z; a.w += s*w.w;
}

// ---------------------------------------------------------------------------
// KA: blocks 0..319: filt2[s][c*128+w] = h2[s] @ s_w2 + s_b2 (h2 inline).
//     blocks 320..369: pack data -> dataA f16 MFMA A-frags (verified r4/r6).
//     block 370: pack MLP weights TRANSPOSED for B-frags:
//       wPackA[((l*2+nt)*16 + cout)*32 + cin] = w_l[cin][cout]  (pad 0)
//       bPackA[(l*2+nt)*16 + cout] = b_l[cout]                  (pad 0)
// ---------------------------------------------------------------------------
__global__ __launch_bounds__(256) void ka_prep(
    const float* __restrict__ data, const float* __restrict__ v0,
    const float* __restrict__ s_w1, const float* __restrict__ s_b1,
    const float* __restrict__ s_w2, const float* __restrict__ s_b2,
    const float* __restrict__ w1, const float* __restrict__ b1,
    const float* __restrict__ w2, const float* __restrict__ b2,
    const float* __restrict__ w3, const float* __restrict__ b3,
    _Float16* __restrict__ dataA, float* __restrict__ f2g,
    _Float16* __restrict__ wPackA, float* __restrict__ bPackA)
{
    const int t  = threadIdx.x;
    const int bx = blockIdx.x;
    if (bx == 370) {
        const float* wsrc[3] = { w1, w2, w3 };
        const float* bsrc[3] = { b1, b2, b3 };
        for (int v = t; v < 3072; v += 256) {
            const int l = v >> 10, rem = v & 1023;
            const int cout = rem >> 5, cin = rem & 31;
            float x = 0.f;
            if (cout < 20 && cin < 20) x = wsrc[l][cin * 20 + cout];
            wPackA[v] = (_Float16)x;
        }
        if (t < 96) {
            const int l = t >> 5, cout = t & 31;
            bPackA[t] = (cout < 20) ? bsrc[l][cout] : 0.f;
        }
        return;
    }
    if (bx >= 320) {
        const int o  = (bx - 320) * 256 + t;       // 0..12799
        const int L  = o & 63, cm = o >> 6;        // cm 0..199
        const int mt = cm & 3, ch = cm >> 2;       // ch 0..49
        const int b  = mt * 16 + (L & 15);
        const int nb = ch * 32 + (L >> 4) * 8;
        const float* src = data + b * N_PTS + nb;
        h8 v;
        #pragma unroll
        for (int j = 0; j < 8; j++) v[j] = (_Float16)src[j];
        *(h8*)(dataA + (size_t)o * 8) = v;
        return;
    }
    const int st  = bx / 10, ct = bx - st * 10;
    const int s0  = st * 16;
    const int col = ct * 256 + t;
    __shared__ __align__(16) float h2t[128][20];   // [i][ss] pad 20

    for (int idx = t; idx < 2048; idx += 256) {
        const int ss = idx >> 7, j = idx & 127;
        float acc = s_b1[j];
        #pragma unroll
        for (int d = 0; d < 8; d++) {
            const float val = v0[(s0 + ss) * 8 + d];
            float sv, cv;
            __sincosf(val, &sv, &cv);
            #pragma unroll
            for (int k = 0; k < 5; k++) {
                acc += sv * s_w1[(d*10 + k)     * WID + j];
                acc += cv * s_w1[(d*10 + 5 + k) * WID + j];
                const float ns = 2.f * sv * cv;
                const float nc = 1.f - 2.f * sv * sv;
                sv = ns; cv = nc;
            }
        }
        h2t[j][ss] = silu_f(acc);
    }
    __syncthreads();

    float4 acc[4];
    #pragma unroll
    for (int qq = 0; qq < 4; qq++) acc[qq] = make_float4(0.f, 0.f, 0.f, 0.f);
    #pragma unroll 4
    for (int i = 0; i < 128; i++) {
        const float wv = s_w2[i * 2560 + col];
        const float4* hh = (const float4*)&h2t[i][0];
        #pragma unroll
        for (int qq = 0; qq < 4; qq++) fma4(acc[qq], wv, hh[qq]);
    }
    const float bias = s_b2[col];
    const float* af = (const float*)acc;
    #pragma unroll
    for (int ss = 0; ss < 16; ss++)
        f2g[(s0 + ss) * 2560 + col] = af[ss] + bias;
}

// ---------------------------------------------------------------------------
// embed: sinusoidal embedding of projected point (single point)
// ---------------------------------------------------------------------------
__device__ __forceinline__ void embed_pt(int n, const float Hm[9], h2v e2[10])
{
    const int i = n / NSIDE;
    const int j = n - i * NSIDE;
    const float x = -1.f + (float)i * (2.f/39.f);
    const float y = -1.f + (float)j * (2.f/39.f);
    const float y0 = Hm[0]*x + Hm[1]*y + Hm[2];
    const float y1 = Hm[3]*x + Hm[4]*y + Hm[5];
    const float y2 = Hm[6]*x + Hm[7]*y + Hm[8];
    const float inv = 1.f / y2;
    const float t0 = y0 * inv, t1 = y1 * inv;
    float e[20];
    float sv0, cv0, sv1, cv1;
    __sincosf(t0, &sv0, &cv0);
    __sincosf(t1, &sv1, &cv1);
    #pragma unroll
    for (int k = 0; k < 5; k++) {
        e[k] = sv0; e[5+k] = cv0; e[10+k] = sv1; e[15+k] = cv1;
        const float ns0 = 2.f*sv0*cv0, nc0 = 1.f - 2.f*sv0*sv0; sv0 = ns0; cv0 = nc0;
        const float ns1 = 2.f*sv1*cv1, nc1 = 1.f - 2.f*sv1*sv1; sv1 = ns1; cv1 = nc1;
    }
    #pragma unroll
    for (int k = 0; k < 10; k++)
        e2[k] = __builtin_amdgcn_cvt_pkrtz(e[2*k], e[2*k+1]);
}

// ---------------------------------------------------------------------------
// K1: grid 1024 = (half, s), 800 pts/block, tiles of 256 (3x256 + 32 tail).
// FULL-MFMA pipeline:
//   embed -> act[256][40] f16 (pads 20..31 zero, K=32)
//   3 MLP layers: D = mfma(act A-frag, weight B-frag) per 16-pt m-tile,
//   in-place act update (wave-private m-tiles -> no inter-layer barriers),
//   layer 3 -> filtB[c][p] (b64 packed writes), z-GEMM via MFMA (r5-r9 path).
// zpart[half][s][c*64+b] raw sums; K2 combines + silu + /N.
// ---------------------------------------------------------------------------
__global__ __launch_bounds__(256) void k1_filt_z(
    const _Float16* __restrict__ dataA, const float* __restrict__ v_last,
    const _Float16* __restrict__ wPackA, const float* __restrict__ bPackA,
    float* __restrict__ zpart)
{
    const int s    = blockIdx.x & 511;
    const int half = blockIdx.x >> 9;
    const int nb0  = half * 800;
    const int t    = threadIdx.x;
    const int lane = t & 63;
    const int w    = t >> 6;
    const int q    = lane >> 4;
    const int l15  = lane & 15;

    __shared__ __align__(16) unsigned char pool[21504];  // act[256][40] f16 / red[4][64][21] f32
    __shared__ __align__(16) _Float16 filtB[20 * 264];   // 10560 B
    _Float16* act = (_Float16*)pool;
    float*    red = (float*)pool;

    // weight B-frags + biases: resident in registers whole kernel
    h8 wf[3][2]; float bv[3][2];
    #pragma unroll
    for (int l = 0; l < 3; l++)
        #pragma unroll
        for (int nt = 0; nt < 2; nt++) {
            wf[l][nt] = *(const h8*)(wPackA + (((l*2+nt)*16 + l15) * 32 + q*8));
            bv[l][nt] = bPackA[(l*2+nt)*16 + l15];
        }

    float Hm[9];
    #pragma unroll
    for (int k = 0; k < 9; k++) Hm[k] = (k == 0 || k == 4 || k == 8) ? 1.f : 0.f;
    #pragma unroll
    for (int k = 0; k < 8; k++) Hm[k] += 0.1f * v_last[s*8 + k];

    f4 zacc[4][2];
    #pragma unroll
    for (int mt = 0; mt < 4; mt++) { zacc[mt][0] = (f4)(0.f); zacc[mt][1] = (f4)(0.f); }
    const f4 zero4 = (f4)(0.f);

    // zero K-pad cols 20..31 of all 256 rows (once; never rewritten)
    {
        unsigned long long* pz = (unsigned long long*)(act + t*40 + 20);
        pz[0] = 0ull; pz[1] = 0ull; pz[2] = 0ull;
    }

    for (int base = 0; base < 800; base += 256) {
        const int tn = min(256, 800 - base);       // 256,256,256,32
        if (t < tn) {
            h2v e2[10];
            embed_pt(nb0 + base + t, Hm, e2);
            #pragma unroll
            for (int k = 0; k < 10; k++)
                *(h2v*)(act + t*40 + 2*k) = e2[k];
        }
        __syncthreads();

        // ---- 3 MFMA MLP layers, in-place, wave-private m-tiles ----
        const int nmt = tn >> 4;
        #pragma unroll
        for (int l = 0; l < 3; l++) {
            for (int mt = w; mt < nmt; mt += 4) {
                const int r0 = mt * 16;
                const h8 af = *(const h8*)(act + (r0 + l15)*40 + q*8);
                f4 D0 = __builtin_amdgcn_mfma_f32_16x16x32_f16(af, wf[l][0], zero4, 0, 0, 0);
                f4 D1 = __builtin_amdgcn_mfma_f32_16x16x32_f16(af, wf[l][1], zero4, 0, 0, 0);
                if (l < 2) {
                    #pragma unroll
                    for (int r = 0; r < 4; r++) {
                        const int p = r0 + q*4 + r;
                        act[p*40 + l15] = (_Float16)silu_f(D0[r] + bv[l][0]);
                        if (l15 < 4)
                            act[p*40 + 16 + l15] = (_Float16)silu_f(D1[r] + bv[l][1]);
                    }
                } else {
                    h4 p0, p1;
                    #pragma unroll
                    for (int r = 0; r < 4; r++) {
                        p0[r] = (_Float16)(D0[r] + bv[2][0]);
                        p1[r] = (_Float16)(D1[r] + bv[2][1]);
                    }
                    *(h4*)(filtB + l15*264 + r0 + q*4) = p0;
                    if (l15 < 4)
                        *(h4*)(filtB + (16 + l15)*264 + r0 + q*4) = p1;
                }
            }
        }
        __syncthreads();   // filtB ready for all waves

        // ---- z-GEMM: MFMA with global dataA A-frags (verified r5-r9) ----
        const int nkc = tn >> 5;   // 8,8,8,1
        const int r1row = (l15 < 4) ? (16 + l15) : 0;
        for (int kc = w; kc < nkc; kc += 4) {
            const int gchunk = ((nb0 + base) >> 5) + kc;
            const h8 bf0 = *(const h8*)(filtB + l15  *264 + kc*32 + q*8);
            const h8 bf1 = *(const h8*)(filtB + r1row*264 + kc*32 + q*8);
            #pragma unroll
            for (int mt = 0; mt < 4; mt++) {
                const h8 afz = *(const h8*)(dataA + ((size_t)(gchunk*4 + mt)*64 + lane)*8);
                zacc[mt][0] = __builtin_amdgcn_mfma_f32_16x16x32_f16(afz, bf0, zacc[mt][0], 0, 0, 0);
                zacc[mt][1] = __builtin_amdgcn_mfma_f32_16x16x32_f16(afz, bf1, zacc[mt][1], 0, 0, 0);
            }
        }
        __syncthreads();   // protect filtB + act for next tile
    }

    // cross-wave K-reduction (red overlays act; safe after trailing barrier)
    #pragma unroll
    for (int mt = 0; mt < 4; mt++) {
        #pragma unroll
        for (int r = 0; r < 4; r++) {
            const int b = mt*16 + q*4 + r;
            red[(w*64 + b)*21 + l15] = zacc[mt][0][r];
            if (l15 < 4) red[(w*64 + b)*21 + 16 + l15] = zacc[mt][1][r];
        }
    }
    __syncthreads();
    for (int v = t; v < 1280; v += 256) {
        const int c = v >> 6, b = v & 63;
        const float sum = red[b*21 + c] + red[(64+b)*21 + c]
                        + red[(128+b)*21 + c] + red[(192+b)*21 + c];
        zpart[(half*512 + s)*1280 + v] = sum;   // raw; silu + /N applied in k2
    }
}

// ---------------------------------------------------------------------------
// K2: grid 256 = (sgrp 128) x (whalf 2). Block: 4 s, 64 w.
// Combines zpart halves + silu + /N, contracts vs filt2 -> part[blk][b][w64]
// ---------------------------------------------------------------------------
__global__ __launch_bounds__(256) void k2_contract(
    const float* __restrict__ zg, const float* __restrict__ f2g,
    float* __restrict__ part)
{
    const int blk = blockIdx.x;
    const int sg  = blk >> 1;
    const int wh  = blk & 1;
    const int s0  = sg * 4;
    const int w0  = wh * 64;
    const int t   = threadIdx.x;
    __shared__ __align__(16) float zl[4*1280];   // [sp][c][b]
    __shared__ __align__(16) float fl[4*20*64];  // [sp][c][w64]
    #pragma unroll
    for (int sp = 0; sp < 4; sp++) {
        const int srow = (s0 + sp) * 1280;
        for (int r = t; r < 1280; r += 256) {
            const float a0 = zg[srow + r];
            const float a1 = zg[512*1280 + srow + r];
            zl[sp*1280 + r] = silu_f((a0 + a1) * (1.f / (float)N_PTS));
        }
        for (int u = t; u < 1280; u += 256) {
            const int c = u >> 6, ww = u & 63;
            fl[sp*1280 + u] = f2g[(s0 + sp)*2560 + c*128 + w0 + ww];
        }
    }
    __syncthreads();
    const int ww = t & 63, bh = t >> 6;
    float4 acc[4];
    #pragma unroll
    for (int qq = 0; qq < 4; qq++) acc[qq] = make_float4(0.f, 0.f, 0.f, 0.f);
    #pragma unroll 4
    for (int sc = 0; sc < 80; sc++) {
        const float f = fl[sc * 64 + ww];
        const float4* zz = (const float4*)&zl[sc * 64 + bh * 16];
        #pragma unroll
        for (int qq = 0; qq < 4; qq++) fma4(acc[qq], f, zz[qq]);
    }
    const float* af = (const float*)acc;
    #pragma unroll
    for (int idx = 0; idx < 16; idx++) {
        const int b = bh * 16 + idx;
        part[blk * 4096 + b * 64 + ww] = af[idx];
    }
}

// ---------------------------------------------------------------------------
// K3: reduce partials over 128 s-groups, then FC tail.
// ---------------------------------------------------------------------------
__global__ __launch_bounds__(128) void k3_tail(
    const float* __restrict__ part,
    const float* __restrict__ fc1w, const float* __restrict__ fc1b,
    const float* __restrict__ fc2w, const float* __restrict__ fc2b,
    const float* __restrict__ pw,   const float* __restrict__ pb,
    float* __restrict__ out)
{
    const int b = blockIdx.x, t = threadIdx.x;
    const int wh = t >> 6, wl = t & 63;
    __shared__ float zb[128], r1[128], r2[128];
    float sum = 0.f;
    #pragma unroll 8
    for (int sg = 0; sg < 128; sg++)
        sum += part[((sg << 1) | wh) * 4096 + b * 64 + wl];
    zb[t] = sum * (1.f / (float)SNUM);
    __syncthreads();
    float a = fc1b[t];
    #pragma unroll 8
    for (int i = 0; i < 128; i++) a += zb[i] * fc1w[i * 128 + t];
    r1[t] = silu_f(a) + zb[t];
    __syncthreads();
    a = fc2b[t];
    #pragma unroll 8
    for (int i = 0; i < 128; i++) a += r1[i] * fc2w[i * 128 + t];
    r2[t] = silu_f(a) + r1[t];
    __syncthreads();
    if (t < 10) {
        float o = pb[t];
        #pragma unroll 8
        for (int i = 0; i < 128; i++) o += r2[i] * pw[i * 10 + t];
        out[b * 10 + t] = o;
    }
}

extern "C" void kernel_launch(void* const* d_in, const int* in_sizes, int n_in,
                              void* d_out, int out_size, void* d_ws, size_t ws_size,
                              hipStream_t stream) {
    const float* data   = (const float*)d_in[0];
    const float* v0     = (const float*)d_in[1];
    const float* v_last = (const float*)d_in[2];
    const float* fl_w1  = (const float*)d_in[3];
    const float* fl_b1  = (const float*)d_in[4];
    const float* fl_w2  = (const float*)d_in[5];
    const float* fl_b2  = (const float*)d_in[6];
    const float* fl_w3  = (const float*)d_in[7];
    const float* fl_b3  = (const float*)d_in[8];
    const float* s_w1   = (const float*)d_in[9];
    const float* s_b1   = (const float*)d_in[10];
    const float* s_w2   = (const float*)d_in[11];
    const float* s_b2   = (const float*)d_in[12];
    const float* fc1_w  = (const float*)d_in[13];
    const float* fc1_b  = (const float*)d_in[14];
    const float* fc2_w  = (const float*)d_in[15];
    const float* fc2_b  = (const float*)d_in[16];
    const float* pool_w = (const float*)d_in[17];
    const float* pool_b = (const float*)d_in[18];
    float* out = (float*)d_out;

    float* ws        = (float*)d_ws;
    _Float16* dataA  = (_Float16*)ws;        // 102400 halves = 51200 float slots
    float* zpart  = ws    + 51200;           // 2*655360 [half][s][c][b] raw
    float* f2g    = zpart + 1310720;         // 1310720  [s][c*128+w]
    float* part   = f2g   + 1310720;         // 1048576  [blk][b][w64]
    _Float16* wPackA = (_Float16*)(part + 1048576);  // 3072 halves = 1536 fslots
    float* bPackA = part + 1048576 + 1536;   // 96 floats
    // total ~14.9 MB

    ka_prep    <<<371, 256, 0, stream>>>(data, v0, s_w1, s_b1, s_w2, s_b2,
                                         fl_w1, fl_b1, fl_w2, fl_b2, fl_w3, fl_b3,
                                         dataA, f2g, wPackA, bPackA);
    k1_filt_z  <<<1024, 256, 0, stream>>>(dataA, v_last, wPackA, bPackA, zpart);
    k2_contract<<<256, 256, 0, stream>>>(zpart, f2g, part);
    k3_tail    <<<64, 128, 0, stream>>>(part, fc1_w, fc1_b, fc2_w, fc2_b,
                                        pool_w, pool_b, out);
}